// Round 8
// baseline (67.483 us; speedup 1.0000x reference)
//
#include <hip/hip_runtime.h>
#include <hip/hip_bf16.h>

#define N_TOTAL 8192
#define B_HALF  4096
#define D       256
#define BM      128
#define BK      64
#define NTILES  (N_TOTAL / BM)               // 64
#define NBLK    (NTILES * (NTILES + 1) / 2)  // 2080
#define NPAIR   (NBLK / 2)                   // 1040
#define PREP_BLOCKS (N_TOTAL / 32)           // 256

typedef __bf16 bf16x8v __attribute__((ext_vector_type(8)));
typedef float  f32x4v  __attribute__((ext_vector_type(4)));

__device__ __forceinline__ unsigned short f2bf(float x) {
    unsigned int u = __float_as_uint(x);
    return (unsigned short)((u + 0x7FFFu + ((u >> 16) & 1u)) >> 16);
}
__device__ __forceinline__ float bf2f(unsigned short b) {
    return __uint_as_float(((unsigned int)b) << 16);
}

__device__ __forceinline__ void gload_lds16(const void* g, void* l) {
    __builtin_amdgcn_global_load_lds(
        (const __attribute__((address_space(1))) unsigned int*)g,
        (__attribute__((address_space(3))) unsigned int*)l,
        16, 0, 0);
}

// ---------------------------------------------------------------------------
// prep: f32 -> bf16 (ws), row norms sq[], per-block column-sum partials and
// per-block sum(sq) partials. NO atomics/tickets/fences; nothing needs
// zero-initialized workspace (everything fully overwritten every call).
// ---------------------------------------------------------------------------
__global__ void prep_kernel(const float* __restrict__ src,
                            const float* __restrict__ tgt,
                            unsigned short* __restrict__ tb,
                            float* __restrict__ sq,
                            float* __restrict__ colsum_part,  // [256][256]
                            double* __restrict__ sumsq_part)  // [256]
{
    __shared__ float colpart[4][256];
    __shared__ double wsum[4];
    int tid = threadIdx.x;
    int wv = tid >> 6, ln = tid & 63;
    int row0 = blockIdx.x * 32 + wv * 8;

    float cp0 = 0.f, cp1 = 0.f, cp2 = 0.f, cp3 = 0.f;
    double dsum = 0.0;

    for (int t = 0; t < 8; ++t) {
        int row = row0 + t;
        const float* p = (row < B_HALF) ? (src + (size_t)row * D)
                                        : (tgt + (size_t)(row - B_HALF) * D);
        float4 v = *(const float4*)(p + ln * 4);
        unsigned short b0 = f2bf(v.x), b1 = f2bf(v.y), b2 = f2bf(v.z), b3 = f2bf(v.w);
        float x0 = bf2f(b0), x1 = bf2f(b1), x2 = bf2f(b2), x3 = bf2f(b3);
        ushort4 u; u.x = b0; u.y = b1; u.z = b2; u.w = b3;
        *(ushort4*)(tb + (size_t)row * D + ln * 4) = u;

        cp0 += x0; cp1 += x1; cp2 += x2; cp3 += x3;

        float sqp = x0 * x0 + x1 * x1 + x2 * x2 + x3 * x3;
        #pragma unroll
        for (int off = 32; off; off >>= 1) sqp += __shfl_down(sqp, off, 64);
        if (ln == 0) { sq[row] = sqp; dsum += (double)sqp; }
    }
    colpart[wv][ln * 4 + 0] = cp0;
    colpart[wv][ln * 4 + 1] = cp1;
    colpart[wv][ln * 4 + 2] = cp2;
    colpart[wv][ln * 4 + 3] = cp3;
    if (ln == 0) wsum[wv] = dsum;
    __syncthreads();
    colsum_part[blockIdx.x * 256 + tid] =
        colpart[0][tid] + colpart[1][tid] + colpart[2][tid] + colpart[3][tid];
    if (tid == 0)
        sumsq_part[blockIdx.x] = wsum[0] + wsum[1] + wsum[2] + wsum[3];
}

// ---------------------------------------------------------------------------
// bw: closed-form bandwidth from the partials.
//   sum(L2) = 2n*sum(sq) - 2*||colsum||^2 ; cexp = log2(e)/(16*bw)
// ---------------------------------------------------------------------------
__global__ void bw_kernel(const float* __restrict__ colsum_part,
                          const double* __restrict__ sumsq_part,
                          float* __restrict__ cexp) {
    __shared__ double red1[256], red2[256];
    int tid = threadIdx.x;
    float cs = 0.f;
    #pragma unroll 4
    for (int b = 0; b < PREP_BLOCKS; ++b)
        cs += colsum_part[b * 256 + tid];          // coalesced across threads
    red1[tid] = sumsq_part[tid];                   // 256 prep blocks
    red2[tid] = (double)cs * (double)cs;
    __syncthreads();
    for (int off = 128; off; off >>= 1) {
        if (tid < off) { red1[tid] += red1[tid + off]; red2[tid] += red2[tid + off]; }
        __syncthreads();
    }
    if (tid == 0) {
        double sl2 = 2.0 * (double)N_TOTAL * red1[0] - 2.0 * red2[0];
        double bw = sl2 / ((double)N_TOTAL * N_TOTAL - (double)N_TOTAL);
        cexp[0] = (float)(1.4426950408889634 / (16.0 * bw));
    }
}

// ---------------------------------------------------------------------------
// mmd: each block = TWO consecutive triangle tiles (128x128), 8 fat K-steps,
// T3-minimum schedule: dbuf LDS, stage(s+1) issued FIRST, then ds_read+MFMA
// of step s, then ONE vmcnt(0)+s_barrier per step. 512 threads (8 waves,
// 32x64 output per wave) -> 2 blocks/CU = 4 waves/SIMD: TLP hides the
// per-step barrier/latency stalls. Plain partials store (no fence/atomic).
// ---------------------------------------------------------------------------
__device__ __forceinline__ void stage_tiles(const unsigned short* __restrict__ tb,
                                            int rowBase, int colBase, int kb0,
                                            int wid, int ln,
                                            unsigned short* ldsA,
                                            unsigned short* ldsB) {
    #pragma unroll
    for (int i = 0; i < 2; ++i) {
        int o = i * 8192 + wid * 1024 + ln * 16;         // linear LDS byte off
        int rowl = o >> 7;                               // 128 B per row
        int colb = (o & 127) ^ ((rowl & 7) << 4);        // pre-swizzled source
        gload_lds16(tb + (size_t)(rowBase + rowl) * D + kb0 + (colb >> 1),
                    (char*)ldsA + i * 8192 + wid * 1024);
        gload_lds16(tb + (size_t)(colBase + rowl) * D + kb0 + (colb >> 1),
                    (char*)ldsB + i * 8192 + wid * 1024);
    }
}

__global__ __launch_bounds__(512, 4)
void mmd_kernel(const unsigned short* __restrict__ tb,
                const float* __restrict__ sq,
                const float* __restrict__ cexp_p,
                double* __restrict__ partials) {
    __shared__ __align__(16) unsigned short lds[2][2][BM * BK];  // 64 KB
    __shared__ float sqi[2][BM], sqj[2][BM];
    __shared__ float redbuf[8];

    // decode pair: tiles t0 = 2*bid, t1 = t0+1 of the lower triangle
    int t0 = blockIdx.x * 2;
    int r0 = (int)((sqrtf(8.0f * (float)t0 + 1.0f) - 1.0f) * 0.5f);
    while ((r0 + 1) * (r0 + 2) / 2 <= t0) ++r0;
    while (r0 * (r0 + 1) / 2 > t0) --r0;
    int c0 = t0 - r0 * (r0 + 1) / 2;
    int r1 = r0, c1 = c0 + 1;
    if (c1 > r0) { r1 = r0 + 1; c1 = 0; }

    const int rowB[2] = {r0 * BM, r1 * BM};
    const int colB[2] = {c0 * BM, c1 * BM};
    // per-tile weight: sign (block-uniform; B_HALF multiple of BM) x triangle
    float wt[2];
    wt[0] = (((r0 < NTILES / 2) == (c0 < NTILES / 2)) ? 1.f : -1.f) * (r0 != c0 ? 2.f : 1.f);
    wt[1] = (((r1 < NTILES / 2) == (c1 < NTILES / 2)) ? 1.f : -1.f) * (r1 != c1 ? 2.f : 1.f);

    int tid = threadIdx.x;
    int wid = tid >> 6, ln = tid & 63;
    int wr = wid >> 1, wc = wid & 1;         // wave tile: rows 32*wr, cols 64*wc
    int lo = ln & 15, hi = ln >> 4;

    // stage step 0 (tile0, ks=0) immediately; overlap sq loads under it
    stage_tiles(tb, rowB[0], colB[0], 0, wid, ln, lds[0][0], lds[0][1]);

    if (tid < BM)            sqi[0][tid]       = sq[rowB[0] + tid];
    else if (tid < 2 * BM)   sqj[0][tid - BM]  = sq[colB[0] + (tid - BM)];
    else if (tid < 3 * BM)   sqi[1][tid - 256] = sq[rowB[1] + (tid - 256)];
    else                     sqj[1][tid - 384] = sq[colB[1] + (tid - 384)];
    float cexp = cexp_p[0];

    __syncthreads();                 // drains vmcnt(0)+lgkmcnt(0): buf0 ready

    f32x4v acc[2][4] = {};
    float tacc = 0.f;

    #pragma unroll
    for (int s = 0; s < 8; ++s) {    // step = (tile = s>>2, ks = s&3)
        const int cur = s & 1;
        const int tile = s >> 2;

        if (s < 7) {                 // issue next step's stage FIRST
            const int tn = (s + 1) >> 2, kn = (s + 1) & 3;
            stage_tiles(tb, rowB[tn], colB[tn], kn * BK, wid, ln,
                        lds[cur ^ 1][0], lds[cur ^ 1][1]);
            __builtin_amdgcn_sched_barrier(0);   // keep stage issue first
        }

        // read this step's fragments (swizzled, conflict-free)
        bf16x8v a[2][2], b[2][4];
        #pragma unroll
        for (int kk = 0; kk < 2; ++kk) {
            #pragma unroll
            for (int mi = 0; mi < 2; ++mi) {
                int rowl = wr * 32 + mi * 16 + lo;
                int colb = (kk * 64 + hi * 16) ^ ((rowl & 7) << 4);
                a[kk][mi] = *(const bf16x8v*)((const char*)lds[cur][0] + rowl * 128 + colb);
            }
            #pragma unroll
            for (int ni = 0; ni < 4; ++ni) {
                int rowl = wc * 64 + ni * 16 + lo;
                int colb = (kk * 64 + hi * 16) ^ ((rowl & 7) << 4);
                b[kk][ni] = *(const bf16x8v*)((const char*)lds[cur][1] + rowl * 128 + colb);
            }
        }

        __builtin_amdgcn_s_setprio(1);
        #pragma unroll
        for (int kk = 0; kk < 2; ++kk)
            #pragma unroll
            for (int mi = 0; mi < 2; ++mi)
                #pragma unroll
                for (int ni = 0; ni < 4; ++ni)
                    acc[mi][ni] = __builtin_amdgcn_mfma_f32_16x16x32_bf16(
                        a[kk][mi], b[kk][ni], acc[mi][ni], 0, 0, 0);
        __builtin_amdgcn_s_setprio(0);

        if ((s & 3) == 3) {
            // epilogue for `tile` (VALU; overlaps the in-flight stage)
            // C/D layout (16x16x32): col = lane&15, row = (lane>>4)*4 + reg
            float ep = 0.f;
            #pragma unroll
            for (int mi = 0; mi < 2; ++mi) {
                float si4[4];
                #pragma unroll
                for (int rg = 0; rg < 4; ++rg)
                    si4[rg] = sqi[tile][wr * 32 + mi * 16 + hi * 4 + rg];
                #pragma unroll
                for (int ni = 0; ni < 4; ++ni) {
                    float sj = sqj[tile][wc * 64 + ni * 16 + lo];
                    #pragma unroll
                    for (int rg = 0; rg < 4; ++rg) {
                        float arg = (2.0f * acc[mi][ni][rg] - (si4[rg] + sj)) * cexp;
                        float e0 = __builtin_amdgcn_exp2f(arg);
                        float e2 = e0 * e0, e4 = e2 * e2, e8 = e4 * e4, e16 = e8 * e8;
                        ep += (e0 + e2) + ((e4 + e8) + e16);
                    }
                }
            }
            tacc += wt[tile] * ep;
            #pragma unroll
            for (int mi = 0; mi < 2; ++mi)
                #pragma unroll
                for (int ni = 0; ni < 4; ++ni)
                    acc[mi][ni] = f32x4v{0.f, 0.f, 0.f, 0.f};
        }

        if (s < 7) {
            asm volatile("s_waitcnt vmcnt(0)" ::: "memory");  // next buf landed
            __builtin_amdgcn_s_barrier();
        }
    }

    // block reduction -> plain partial store (no fence, no atomic)
    #pragma unroll
    for (int off = 32; off; off >>= 1) tacc += __shfl_down(tacc, off, 64);
    if (ln == 0) redbuf[wid] = tacc;
    __syncthreads();
    if (tid == 0) {
        float bsum = 0.f;
        #pragma unroll
        for (int w = 0; w < 8; ++w) bsum += redbuf[w];
        partials[blockIdx.x] = (double)bsum;
    }
}

// ---------------------------------------------------------------------------
__global__ void final_kernel(const double* __restrict__ partials,
                             float* __restrict__ out) {
    __shared__ double dred[256];
    int tid = threadIdx.x;
    double d = 0.0;
    for (int i = tid; i < NPAIR; i += 256) d += partials[i];
    dred[tid] = d;
    __syncthreads();
    for (int off = 128; off; off >>= 1) {
        if (tid < off) dred[tid] += dred[tid + off];
        __syncthreads();
    }
    if (tid == 0)
        out[0] = (float)(dred[0] / (5.0 * (double)B_HALF * (double)B_HALF));
}

// ---------------------------------------------------------------------------
extern "C" void kernel_launch(void* const* d_in, const int* in_sizes, int n_in,
                              void* d_out, int out_size, void* d_ws, size_t ws_size,
                              hipStream_t stream) {
    const float* src = (const float*)d_in[0];
    const float* tgt = (const float*)d_in[1];
    float* out = (float*)d_out;
    char* ws = (char*)d_ws;

    // all ws buffers are fully overwritten every call -> NO memset node
    float*  cexp     = (float*)(ws + 16);
    double* ssqpart  = (double*)(ws + 2048);    // 256 f64
    float*  sq       = (float*)(ws + 4096);     // 8192 f32 (ends 36864)
    double* partials = (double*)(ws + 36864);   // 1040 f64 (ends 45184)
    float*  cspart   = (float*)(ws + 131072);   // 256*256 f32 (ends 393216)
    unsigned short* tb = (unsigned short*)(ws + 1048576);  // 4 MB bf16

    prep_kernel<<<PREP_BLOCKS, 256, 0, stream>>>(src, tgt, tb, sq, cspart,
                                                 ssqpart);
    bw_kernel<<<1, 256, 0, stream>>>(cspart, ssqpart, cexp);
    mmd_kernel<<<NPAIR, 512, 0, stream>>>(tb, sq, cexp, partials);
    final_kernel<<<1, 256, 0, stream>>>(partials, out);
}

// Round 9
// 59.852 us; speedup vs baseline: 1.1275x; 1.1275x over previous
//
#include <hip/hip_runtime.h>
#include <hip/hip_bf16.h>

#define N_TOTAL 8192
#define B_HALF  4096
#define D       256
#define BM      128
#define NTILES  (N_TOTAL / BM)               // 64
#define NBLK    (NTILES * (NTILES + 1) / 2)  // 2080
#define PREP_BLOCKS (N_TOTAL / 32)           // 256

typedef __bf16 bf16x8v __attribute__((ext_vector_type(8)));
typedef float  f32x4v  __attribute__((ext_vector_type(4)));

__device__ __forceinline__ unsigned short f2bf(float x) {
    unsigned int u = __float_as_uint(x);
    return (unsigned short)((u + 0x7FFFu + ((u >> 16) & 1u)) >> 16);
}
__device__ __forceinline__ float bf2f(unsigned short b) {
    return __uint_as_float(((unsigned int)b) << 16);
}

// ---------------------------------------------------------------------------
// prep: f32 -> bf16 in K-PANEL-MAJOR layout tb2[k>>3][row][k&7], row norms
// sq[], per-block column-sum partials, per-block sum(sq) partials. No
// atomics/tickets/fences; all outputs fully overwritten every call.
// Thread (ln) holds k = 4ln..4ln+3 of a row -> one 8B store into
// tb2[(ln>>1)][row][(ln&1)*4 .. +3].
// ---------------------------------------------------------------------------
__global__ void prep_kernel(const float* __restrict__ src,
                            const float* __restrict__ tgt,
                            unsigned short* __restrict__ tb2,
                            float* __restrict__ sq,
                            float* __restrict__ colsum_part,  // [256][256]
                            double* __restrict__ sumsq_part)  // [256]
{
    __shared__ float colpart[4][256];
    __shared__ double wsum[4];
    int tid = threadIdx.x;
    int wv = tid >> 6, ln = tid & 63;
    int row0 = blockIdx.x * 32 + wv * 8;

    float cp0 = 0.f, cp1 = 0.f, cp2 = 0.f, cp3 = 0.f;
    double dsum = 0.0;

    for (int t = 0; t < 8; ++t) {
        int row = row0 + t;
        const float* p = (row < B_HALF) ? (src + (size_t)row * D)
                                        : (tgt + (size_t)(row - B_HALF) * D);
        float4 v = *(const float4*)(p + ln * 4);
        unsigned short b0 = f2bf(v.x), b1 = f2bf(v.y), b2 = f2bf(v.z), b3 = f2bf(v.w);
        float x0 = bf2f(b0), x1 = bf2f(b1), x2 = bf2f(b2), x3 = bf2f(b3);
        ushort4 u; u.x = b0; u.y = b1; u.z = b2; u.w = b3;
        // K-panel-major store: chunk = ln>>1, element base = (ln&1)*4
        *(ushort4*)(tb2 + ((size_t)(ln >> 1) * N_TOTAL + row) * 8 + (ln & 1) * 4) = u;

        cp0 += x0; cp1 += x1; cp2 += x2; cp3 += x3;

        float sqp = x0 * x0 + x1 * x1 + x2 * x2 + x3 * x3;
        #pragma unroll
        for (int off = 32; off; off >>= 1) sqp += __shfl_down(sqp, off, 64);
        if (ln == 0) { sq[row] = sqp; dsum += (double)sqp; }
    }
    colpart[wv][ln * 4 + 0] = cp0;
    colpart[wv][ln * 4 + 1] = cp1;
    colpart[wv][ln * 4 + 2] = cp2;
    colpart[wv][ln * 4 + 3] = cp3;
    if (ln == 0) wsum[wv] = dsum;
    __syncthreads();
    colsum_part[blockIdx.x * 256 + tid] =
        colpart[0][tid] + colpart[1][tid] + colpart[2][tid] + colpart[3][tid];
    if (tid == 0)
        sumsq_part[blockIdx.x] = wsum[0] + wsum[1] + wsum[2] + wsum[3];
}

// ---------------------------------------------------------------------------
// bw: closed-form bandwidth from the partials.
//   sum(L2) = 2n*sum(sq) - 2*||colsum||^2 ; cexp = log2(e)/(16*bw)
// ---------------------------------------------------------------------------
__global__ void bw_kernel(const float* __restrict__ colsum_part,
                          const double* __restrict__ sumsq_part,
                          float* __restrict__ cexp) {
    __shared__ double red1[256], red2[256];
    int tid = threadIdx.x;
    float cs = 0.f;
    #pragma unroll 8
    for (int b = 0; b < PREP_BLOCKS; ++b)
        cs += colsum_part[b * 256 + tid];          // coalesced across threads
    red1[tid] = sumsq_part[tid];                   // 256 prep blocks
    red2[tid] = (double)cs * (double)cs;
    __syncthreads();
    for (int off = 128; off; off >>= 1) {
        if (tid < off) { red1[tid] += red1[tid + off]; red2[tid] += red2[tid + off]; }
        __syncthreads();
    }
    if (tid == 0) {
        double sl2 = 2.0 * (double)N_TOTAL * red1[0] - 2.0 * red2[0];
        double bw = sl2 / ((double)N_TOTAL * N_TOTAL - (double)N_TOTAL);
        cexp[0] = (float)(1.4426950408889634 / (16.0 * bw));
    }
}

// ---------------------------------------------------------------------------
// mmd: one 128x128 lower-triangle Gram tile per block; MFMA fragments loaded
// DIRECTLY from global in K-panel-major layout: each wave-load is 64 lanes x
// 16B = 1 KB fully contiguous (16 fully-used cache lines) -> no LDS staging,
// no K-loop barriers, no vmcnt drains. 1-deep register double-buffer over
// 8 kk-steps; waves free-run, TLP (no LDS -> 3+ blocks/CU) hides L2 latency.
// Fused exp epilogue; plain per-block partial store.
// ---------------------------------------------------------------------------
__global__ __launch_bounds__(256)
void mmd_kernel(const unsigned short* __restrict__ tb2,
                const float* __restrict__ sq,
                const float* __restrict__ cexp_p,
                double* __restrict__ partials) {
    __shared__ float sqi[BM], sqj[BM];
    __shared__ float redbuf[4];

    // triangle decode: block t -> (r,c), r >= c
    int t = blockIdx.x;
    int r = (int)((sqrtf(8.0f * (float)t + 1.0f) - 1.0f) * 0.5f);
    while ((r + 1) * (r + 2) / 2 <= t) ++r;
    while (r * (r + 1) / 2 > t) --r;
    int c = t - r * (r + 1) / 2;
    int rowBase = r * BM, colBase = c * BM;

    int tid = threadIdx.x;
    int wv = tid >> 6, ln = tid & 63;
    int wr = wv >> 1, wc = wv & 1;
    int lo = ln & 15, hi = ln >> 4;

    if (tid < BM) sqi[tid] = sq[rowBase + tid];
    else          sqj[tid - BM] = sq[colBase + (tid - BM)];
    float cexp = cexp_p[0];
    __syncthreads();                 // only pre-epilogue barrier

    // fragment base pointers: frag(kk, f) at p + kk*KKSTRIDE + f*256B
    // (lane lo+16*hi: row = base + f*16 + lo, k-chunk = kk*4 + hi)
    const char* pa = (const char*)tb2 +
        ((size_t)hi * N_TOTAL + rowBase + wr * 64 + lo) * 16;
    const char* pb = (const char*)tb2 +
        ((size_t)hi * N_TOTAL + colBase + wc * 64 + lo) * 16;
    const size_t KKSTRIDE = (size_t)4 * N_TOTAL * 16;   // 512 KB

    f32x4v acc[4][4] = {};
    bf16x8v a[2][4], b[2][4];

    #pragma unroll
    for (int mi = 0; mi < 4; ++mi) a[0][mi] = *(const bf16x8v*)(pa + mi * 256);
    #pragma unroll
    for (int ni = 0; ni < 4; ++ni) b[0][ni] = *(const bf16x8v*)(pb + ni * 256);

    #pragma unroll
    for (int kk = 0; kk < 8; ++kk) {        // K = 8 x 32
        const int cur = kk & 1, nxt = cur ^ 1;
        if (kk < 7) {
            const char* qa = pa + (size_t)(kk + 1) * KKSTRIDE;
            const char* qb = pb + (size_t)(kk + 1) * KKSTRIDE;
            #pragma unroll
            for (int mi = 0; mi < 4; ++mi)
                a[nxt][mi] = *(const bf16x8v*)(qa + mi * 256);
            #pragma unroll
            for (int ni = 0; ni < 4; ++ni)
                b[nxt][ni] = *(const bf16x8v*)(qb + ni * 256);
        }
        #pragma unroll
        for (int mi = 0; mi < 4; ++mi)
            #pragma unroll
            for (int ni = 0; ni < 4; ++ni)
                acc[mi][ni] = __builtin_amdgcn_mfma_f32_16x16x32_bf16(
                    a[cur][mi], b[cur][ni], acc[mi][ni], 0, 0, 0);
    }

    // epilogue: arg = (2*gram - (sq_i+sq_j)) * cexp ; kernels e0..e0^16
    // C/D layout (16x16x32): col = lane&15, row = (lane>>4)*4 + reg
    float tacc = 0.f;
    #pragma unroll
    for (int mi = 0; mi < 4; ++mi) {
        float si4[4];
        #pragma unroll
        for (int rg = 0; rg < 4; ++rg)
            si4[rg] = sqi[wr * 64 + mi * 16 + hi * 4 + rg];
        #pragma unroll
        for (int ni = 0; ni < 4; ++ni) {
            float sj = sqj[wc * 64 + ni * 16 + lo];
            #pragma unroll
            for (int rg = 0; rg < 4; ++rg) {
                float arg = (2.0f * acc[mi][ni][rg] - (si4[rg] + sj)) * cexp;
                float e0 = __builtin_amdgcn_exp2f(arg);
                float e2 = e0 * e0, e4 = e2 * e2, e8 = e4 * e4, e16 = e8 * e8;
                tacc += (e0 + e2) + ((e4 + e8) + e16);
            }
        }
    }
    // tile-uniform sign (B_HALF is a multiple of BM) + triangle weight
    float w = ((r < NTILES / 2) == (c < NTILES / 2)) ? 1.f : -1.f;
    if (r != c) w *= 2.f;
    tacc *= w;

    // block reduction -> plain partial store (no fence, no atomic)
    #pragma unroll
    for (int off = 32; off; off >>= 1) tacc += __shfl_down(tacc, off, 64);
    if (ln == 0) redbuf[wv] = tacc;
    __syncthreads();
    if (tid == 0)
        partials[blockIdx.x] =
            (double)(redbuf[0] + redbuf[1] + redbuf[2] + redbuf[3]);
}

// ---------------------------------------------------------------------------
__global__ void final_kernel(const double* __restrict__ partials,
                             float* __restrict__ out) {
    __shared__ double dred[256];
    int tid = threadIdx.x;
    double d = 0.0;
    for (int i = tid; i < NBLK; i += 256) d += partials[i];
    dred[tid] = d;
    __syncthreads();
    for (int off = 128; off; off >>= 1) {
        if (tid < off) dred[tid] += dred[tid + off];
        __syncthreads();
    }
    if (tid == 0)
        out[0] = (float)(dred[0] / (5.0 * (double)B_HALF * (double)B_HALF));
}

// ---------------------------------------------------------------------------
extern "C" void kernel_launch(void* const* d_in, const int* in_sizes, int n_in,
                              void* d_out, int out_size, void* d_ws, size_t ws_size,
                              hipStream_t stream) {
    const float* src = (const float*)d_in[0];
    const float* tgt = (const float*)d_in[1];
    float* out = (float*)d_out;
    char* ws = (char*)d_ws;

    // all ws buffers are fully overwritten every call -> NO memset node
    float*  cexp     = (float*)(ws + 16);
    double* ssqpart  = (double*)(ws + 2048);    // 256 f64
    float*  sq       = (float*)(ws + 4096);     // 8192 f32 (ends 36864)
    double* partials = (double*)(ws + 36864);   // 2080 f64 (ends 53504)
    float*  cspart   = (float*)(ws + 131072);   // 256*256 f32 (ends 393216)
    unsigned short* tb2 = (unsigned short*)(ws + 1048576);  // 4 MB bf16, K-panel-major

    prep_kernel<<<PREP_BLOCKS, 256, 0, stream>>>(src, tgt, tb2, sq, cspart,
                                                 ssqpart);
    bw_kernel<<<1, 256, 0, stream>>>(cspart, ssqpart, cexp);
    mmd_kernel<<<NBLK, 256, 0, stream>>>(tb2, sq, cexp, partials);
    final_kernel<<<1, 256, 0, stream>>>(partials, out);
}

// Round 10
// 58.764 us; speedup vs baseline: 1.1484x; 1.0185x over previous
//
#include <hip/hip_runtime.h>
#include <hip/hip_bf16.h>

#define N_TOTAL 8192
#define B_HALF  4096
#define D       256
#define BM      128
#define NTILES  (N_TOTAL / BM)               // 64
#define NBLK    (NTILES * (NTILES + 1) / 2)  // 2080
#define PREP_BLOCKS (N_TOTAL / 32)           // 256

typedef __bf16 bf16x8v __attribute__((ext_vector_type(8)));
typedef float  f32x4v  __attribute__((ext_vector_type(4)));

__device__ __forceinline__ unsigned short f2bf(float x) {
    unsigned int u = __float_as_uint(x);
    return (unsigned short)((u + 0x7FFFu + ((u >> 16) & 1u)) >> 16);
}
__device__ __forceinline__ float bf2f(unsigned short b) {
    return __uint_as_float(((unsigned int)b) << 16);
}

// ---------------------------------------------------------------------------
// prep: f32 -> bf16 in K-PANEL-MAJOR layout tb2[k>>3][row][k&7], row norms
// sq[], per-block column-sum partials, per-block sum(sq) partials. No
// atomics/tickets/fences; all outputs fully overwritten every call.
// ---------------------------------------------------------------------------
__global__ void prep_kernel(const float* __restrict__ src,
                            const float* __restrict__ tgt,
                            unsigned short* __restrict__ tb2,
                            float* __restrict__ sq,
                            float* __restrict__ colsum_part,  // [256][256]
                            double* __restrict__ sumsq_part)  // [256]
{
    __shared__ float colpart[4][256];
    __shared__ double wsum[4];
    int tid = threadIdx.x;
    int wv = tid >> 6, ln = tid & 63;
    int row0 = blockIdx.x * 32 + wv * 8;

    float cp0 = 0.f, cp1 = 0.f, cp2 = 0.f, cp3 = 0.f;
    double dsum = 0.0;

    for (int t = 0; t < 8; ++t) {
        int row = row0 + t;
        const float* p = (row < B_HALF) ? (src + (size_t)row * D)
                                        : (tgt + (size_t)(row - B_HALF) * D);
        float4 v = *(const float4*)(p + ln * 4);
        unsigned short b0 = f2bf(v.x), b1 = f2bf(v.y), b2 = f2bf(v.z), b3 = f2bf(v.w);
        float x0 = bf2f(b0), x1 = bf2f(b1), x2 = bf2f(b2), x3 = bf2f(b3);
        ushort4 u; u.x = b0; u.y = b1; u.z = b2; u.w = b3;
        // K-panel-major store: chunk = ln>>1, element base = (ln&1)*4
        *(ushort4*)(tb2 + ((size_t)(ln >> 1) * N_TOTAL + row) * 8 + (ln & 1) * 4) = u;

        cp0 += x0; cp1 += x1; cp2 += x2; cp3 += x3;

        float sqp = x0 * x0 + x1 * x1 + x2 * x2 + x3 * x3;
        #pragma unroll
        for (int off = 32; off; off >>= 1) sqp += __shfl_down(sqp, off, 64);
        if (ln == 0) { sq[row] = sqp; dsum += (double)sqp; }
    }
    colpart[wv][ln * 4 + 0] = cp0;
    colpart[wv][ln * 4 + 1] = cp1;
    colpart[wv][ln * 4 + 2] = cp2;
    colpart[wv][ln * 4 + 3] = cp3;
    if (ln == 0) wsum[wv] = dsum;
    __syncthreads();
    colsum_part[blockIdx.x * 256 + tid] =
        colpart[0][tid] + colpart[1][tid] + colpart[2][tid] + colpart[3][tid];
    if (tid == 0)
        sumsq_part[blockIdx.x] = wsum[0] + wsum[1] + wsum[2] + wsum[3];
}

// ---------------------------------------------------------------------------
// bw: closed-form bandwidth from the partials.
//   sum(L2) = 2n*sum(sq) - 2*||colsum||^2 ; cexp = log2(e)/(16*bw)
// ---------------------------------------------------------------------------
__global__ void bw_kernel(const float* __restrict__ colsum_part,
                          const double* __restrict__ sumsq_part,
                          float* __restrict__ cexp) {
    __shared__ double red1[256], red2[256];
    int tid = threadIdx.x;
    float cs = 0.f;
    #pragma unroll 8
    for (int b = 0; b < PREP_BLOCKS; ++b)
        cs += colsum_part[b * 256 + tid];          // coalesced across threads
    red1[tid] = sumsq_part[tid];                   // 256 prep blocks
    red2[tid] = (double)cs * (double)cs;
    __syncthreads();
    for (int off = 128; off; off >>= 1) {
        if (tid < off) { red1[tid] += red1[tid + off]; red2[tid] += red2[tid + off]; }
        __syncthreads();
    }
    if (tid == 0) {
        double sl2 = 2.0 * (double)N_TOTAL * red1[0] - 2.0 * red2[0];
        double bw = sl2 / ((double)N_TOTAL * N_TOTAL - (double)N_TOTAL);
        cexp[0] = (float)(1.4426950408889634 / (16.0 * bw));
    }
}

// ---------------------------------------------------------------------------
// mmd: one 128x128 lower-triangle Gram tile per block; MFMA fragments loaded
// DIRECTLY from global in K-panel-major layout (1 KB contiguous per
// wave-load). SINGLE-buffered fragments (a[4],b[4] scoped per kk) to cut
// VGPR below 128; __launch_bounds__(256,4) -> 4 waves/SIMD (16 waves/CU):
// per-step L2 latency is hidden by co-resident waves (TLP) instead of
// register prefetch (ILP). No LDS staging, no K-loop barriers.
// ---------------------------------------------------------------------------
__global__ __launch_bounds__(256, 4)
void mmd_kernel(const unsigned short* __restrict__ tb2,
                const float* __restrict__ sq,
                const float* __restrict__ cexp_p,
                double* __restrict__ partials) {
    __shared__ float sqi[BM], sqj[BM];
    __shared__ float redbuf[4];

    // triangle decode: block t -> (r,c), r >= c
    int t = blockIdx.x;
    int r = (int)((sqrtf(8.0f * (float)t + 1.0f) - 1.0f) * 0.5f);
    while ((r + 1) * (r + 2) / 2 <= t) ++r;
    while (r * (r + 1) / 2 > t) --r;
    int c = t - r * (r + 1) / 2;
    int rowBase = r * BM, colBase = c * BM;

    int tid = threadIdx.x;
    int wv = tid >> 6, ln = tid & 63;
    int wr = wv >> 1, wc = wv & 1;
    int lo = ln & 15, hi = ln >> 4;

    float cexp = cexp_p[0];
    // pre-scale by cexp so the epilogue inner op is a single fma
    if (tid < BM) sqi[tid] = sq[rowBase + tid] * cexp;
    else          sqj[tid - BM] = sq[colBase + (tid - BM)] * cexp;
    __syncthreads();                 // only pre-epilogue barrier

    // fragment base pointers: frag(kk, f) at p + kk*KKSTRIDE + f*256B
    // (lane lo+16*hi: row = base + f*16 + lo, k-chunk = kk*4 + hi)
    const char* pa = (const char*)tb2 +
        ((size_t)hi * N_TOTAL + rowBase + wr * 64 + lo) * 16;
    const char* pb = (const char*)tb2 +
        ((size_t)hi * N_TOTAL + colBase + wc * 64 + lo) * 16;
    const size_t KKSTRIDE = (size_t)4 * N_TOTAL * 16;   // 512 KB

    f32x4v acc[4][4] = {};

    #pragma unroll
    for (int kk = 0; kk < 8; ++kk) {        // K = 8 x 32
        bf16x8v a[4], b[4];
        const char* qa = pa + (size_t)kk * KKSTRIDE;
        const char* qb = pb + (size_t)kk * KKSTRIDE;
        #pragma unroll
        for (int mi = 0; mi < 4; ++mi) a[mi] = *(const bf16x8v*)(qa + mi * 256);
        #pragma unroll
        for (int ni = 0; ni < 4; ++ni) b[ni] = *(const bf16x8v*)(qb + ni * 256);

        __builtin_amdgcn_s_setprio(1);
        #pragma unroll
        for (int mi = 0; mi < 4; ++mi)
            #pragma unroll
            for (int ni = 0; ni < 4; ++ni)
                acc[mi][ni] = __builtin_amdgcn_mfma_f32_16x16x32_bf16(
                    a[mi], b[ni], acc[mi][ni], 0, 0, 0);
        __builtin_amdgcn_s_setprio(0);
    }

    // epilogue: arg = 2*cexp*gram - (sqc_i + sqc_j) ; kernels e0..e0^16
    // C/D layout (16x16x32): col = lane&15, row = (lane>>4)*4 + reg
    float c2 = 2.0f * cexp;
    float tacc = 0.f;
    #pragma unroll
    for (int mi = 0; mi < 4; ++mi) {
        float si4[4];
        #pragma unroll
        for (int rg = 0; rg < 4; ++rg)
            si4[rg] = sqi[wr * 64 + mi * 16 + hi * 4 + rg];
        #pragma unroll
        for (int ni = 0; ni < 4; ++ni) {
            float sj = sqj[wc * 64 + ni * 16 + lo];
            float ss[4];
            #pragma unroll
            for (int rg = 0; rg < 4; ++rg) ss[rg] = si4[rg] + sj;
            #pragma unroll
            for (int rg = 0; rg < 4; ++rg) {
                float arg = __builtin_fmaf(acc[mi][ni][rg], c2, -ss[rg]);
                float e0 = __builtin_amdgcn_exp2f(arg);
                float e2 = e0 * e0, e4 = e2 * e2, e8 = e4 * e4, e16 = e8 * e8;
                tacc += (e0 + e2) + ((e4 + e8) + e16);
            }
        }
    }
    // tile-uniform sign (B_HALF is a multiple of BM) + triangle weight
    float w = ((r < NTILES / 2) == (c < NTILES / 2)) ? 1.f : -1.f;
    if (r != c) w *= 2.f;
    tacc *= w;

    // block reduction -> plain partial store (no fence, no atomic)
    #pragma unroll
    for (int off = 32; off; off >>= 1) tacc += __shfl_down(tacc, off, 64);
    if (ln == 0) redbuf[wv] = tacc;
    __syncthreads();
    if (tid == 0)
        partials[blockIdx.x] =
            (double)(redbuf[0] + redbuf[1] + redbuf[2] + redbuf[3]);
}

// ---------------------------------------------------------------------------
__global__ void final_kernel(const double* __restrict__ partials,
                             float* __restrict__ out) {
    __shared__ double dred[256];
    int tid = threadIdx.x;
    double d = 0.0;
    for (int i = tid; i < NBLK; i += 256) d += partials[i];
    dred[tid] = d;
    __syncthreads();
    for (int off = 128; off; off >>= 1) {
        if (tid < off) dred[tid] += dred[tid + off];
        __syncthreads();
    }
    if (tid == 0)
        out[0] = (float)(dred[0] / (5.0 * (double)B_HALF * (double)B_HALF));
}

// ---------------------------------------------------------------------------
extern "C" void kernel_launch(void* const* d_in, const int* in_sizes, int n_in,
                              void* d_out, int out_size, void* d_ws, size_t ws_size,
                              hipStream_t stream) {
    const float* src = (const float*)d_in[0];
    const float* tgt = (const float*)d_in[1];
    float* out = (float*)d_out;
    char* ws = (char*)d_ws;

    // all ws buffers are fully overwritten every call -> NO memset node
    float*  cexp     = (float*)(ws + 16);
    double* ssqpart  = (double*)(ws + 2048);    // 256 f64
    float*  sq       = (float*)(ws + 4096);     // 8192 f32 (ends 36864)
    double* partials = (double*)(ws + 36864);   // 2080 f64 (ends 53504)
    float*  cspart   = (float*)(ws + 131072);   // 256*256 f32 (ends 393216)
    unsigned short* tb2 = (unsigned short*)(ws + 1048576);  // 4 MB bf16, K-panel-major

    prep_kernel<<<PREP_BLOCKS, 256, 0, stream>>>(src, tgt, tb2, sq, cspart,
                                                 ssqpart);
    bw_kernel<<<1, 256, 0, stream>>>(cspart, ssqpart, cexp);
    mmd_kernel<<<NBLK, 256, 0, stream>>>(tb2, sq, cexp, partials);
    final_kernel<<<1, 256, 0, stream>>>(partials, out);
}